// Round 1
// baseline (288.441 us; speedup 1.0000x reference)
//
#include <hip/hip_runtime.h>
#include <math.h>

#define V 8192
#define D 128
#define NH 8
#define HD 16
#define SEQ 128
#define HID 341
#define EPS 1e-6f

__device__ __forceinline__ float sigm(float x) { return 1.0f / (1.0f + expf(-x)); }

// x[s,d] = sigmoid(w_raw[d, idx[s]])
__global__ __launch_bounds__(256) void k_embed(const int* __restrict__ idx,
                                               const float* __restrict__ w_raw,
                                               float* __restrict__ x) {
    int g = blockIdx.x * 256 + threadIdx.x;   // 16384 total
    int d = g & (D - 1);
    int s = g >> 7;
    x[s * D + d] = sigm(w_raw[d * V + idx[s]]);
}

// inv_norm[v] = 1/||sigmoid(w_raw[:,v])||_2
__global__ __launch_bounds__(256) void k_vnorm(const float* __restrict__ w_raw,
                                               float* __restrict__ inv_norm) {
    int v = blockIdx.x * 256 + threadIdx.x;
    float acc = 0.f;
    for (int d = 0; d < D; ++d) {
        float t = sigm(w_raw[d * V + v]);
        acc += t * t;
    }
    inv_norm[v] = 1.0f / sqrtf(acc);
}

// Per-row: rmsnorm -> q,k,v projections -> rope on q,k.  grid=S, block=D
__global__ __launch_bounds__(128) void k_rms_qkv_rope(
    const float* __restrict__ x, const float* __restrict__ wq,
    const float* __restrict__ wk, const float* __restrict__ wv,
    const float* __restrict__ nw, float* __restrict__ q, float* __restrict__ k,
    float* __restrict__ v) {
    __shared__ float red[D], hr[D], qrow[D], krow[D];
    int s = blockIdx.x, j = threadIdx.x;
    float xv = x[s * D + j];
    red[j] = xv * xv;
    __syncthreads();
    for (int off = 64; off > 0; off >>= 1) {
        if (j < off) red[j] += red[j + off];
        __syncthreads();
    }
    float r = 1.0f / sqrtf(red[0] * (1.0f / D) + EPS);
    hr[j] = xv * r * nw[j];
    __syncthreads();
    float qa = 0.f, ka = 0.f, va = 0.f;
    for (int d = 0; d < D; ++d) {
        float hv = hr[d];
        qa += hv * wq[d * D + j];
        ka += hv * wk[d * D + j];
        va += hv * wv[d * D + j];
    }
    v[s * D + j] = va;
    qrow[j] = qa;
    krow[j] = ka;
    __syncthreads();
    int c = j & (HD - 1);
    int m = c >> 1;
    // angle = s * 10000^(-m/8)
    float fr = (float)s * expf(-(float)m * 1.15129254649702283e+00f);
    float cs = cosf(fr), sn = sinf(fr);
    int base = j & ~1;
    float qe = qrow[base], qo = qrow[base + 1];
    float ke = krow[base], ko = krow[base + 1];
    float qr = (c & 1) ? (qe * sn + qo * cs) : (qe * cs - qo * sn);
    float kr = (c & 1) ? (ke * sn + ko * cs) : (ke * cs - ko * sn);
    q[s * D + j] = qr;
    k[s * D + j] = kr;
}

// One block per head; thread = query row; two-pass softmax.  grid=NH, block=SEQ
__global__ __launch_bounds__(128) void k_attn(const float* __restrict__ q,
                                              const float* __restrict__ k,
                                              const float* __restrict__ v,
                                              float* __restrict__ o) {
    __shared__ float kh[SEQ][HD], vh[SEQ][HD];
    int h = blockIdx.x, i = threadIdx.x;
    #pragma unroll
    for (int c = 0; c < HD; c += 4) {
        *(float4*)&kh[i][c] = *(const float4*)&k[i * D + h * HD + c];
        *(float4*)&vh[i][c] = *(const float4*)&v[i * D + h * HD + c];
    }
    float qe[HD];
    #pragma unroll
    for (int c = 0; c < HD; ++c) qe[c] = q[i * D + h * HD + c];
    __syncthreads();
    const float scale = 0.25f;
    float mmax = -1e30f;
    for (int jj = 0; jj <= i; ++jj) {
        float dot = 0.f;
        #pragma unroll
        for (int c = 0; c < HD; ++c) dot += qe[c] * kh[jj][c];
        mmax = fmaxf(mmax, dot * scale);
    }
    float l = 0.f;
    float oa[HD];
    #pragma unroll
    for (int c = 0; c < HD; ++c) oa[c] = 0.f;
    for (int jj = 0; jj <= i; ++jj) {
        float dot = 0.f;
        #pragma unroll
        for (int c = 0; c < HD; ++c) dot += qe[c] * kh[jj][c];
        float p = expf(dot * scale - mmax);
        l += p;
        #pragma unroll
        for (int c = 0; c < HD; ++c) oa[c] += p * vh[jj][c];
    }
    float rl = 1.0f / l;
    #pragma unroll
    for (int c = 0; c < HD; ++c) o[i * D + h * HD + c] = oa[c] * rl;
}

// x += o@wo ; h2 = rmsnorm(x) ; a = silu(h2@w1)*(h2@w3).  grid=S, block=D
__global__ __launch_bounds__(128) void k_wo_res_ffn1(
    float* __restrict__ x, const float* __restrict__ o,
    const float* __restrict__ wo, const float* __restrict__ n2w,
    const float* __restrict__ w1, const float* __restrict__ w3,
    float* __restrict__ a) {
    __shared__ float orow[D], red[D], h2[D];
    int s = blockIdx.x, j = threadIdx.x;
    orow[j] = o[s * D + j];
    __syncthreads();
    float acc = 0.f;
    for (int d = 0; d < D; ++d) acc += orow[d] * wo[d * D + j];
    float xn = x[s * D + j] + acc;
    x[s * D + j] = xn;
    red[j] = xn * xn;
    __syncthreads();
    for (int off = 64; off > 0; off >>= 1) {
        if (j < off) red[j] += red[j + off];
        __syncthreads();
    }
    float r = 1.0f / sqrtf(red[0] * (1.0f / D) + EPS);
    h2[j] = xn * r * n2w[j];
    __syncthreads();
    for (int t = j; t < HID; t += D) {
        float a1 = 0.f, a3 = 0.f;
        for (int d = 0; d < D; ++d) {
            float hv = h2[d];
            a1 += hv * w1[d * HID + t];
            a3 += hv * w3[d * HID + t];
        }
        float sl = a1 / (1.0f + expf(-a1));  // silu
        a[s * HID + t] = sl * a3;
    }
}

// x += a@w2.  grid=S, block=D
__global__ __launch_bounds__(128) void k_ffn2(float* __restrict__ x,
                                              const float* __restrict__ a,
                                              const float* __restrict__ w2) {
    __shared__ float ar[HID];
    int s = blockIdx.x, j = threadIdx.x;
    for (int t = j; t < HID; t += D) ar[t] = a[s * HID + t];
    __syncthreads();
    float acc = 0.f;
    for (int t = 0; t < HID; ++t) acc += ar[t] * w2[t * D + j];
    x[s * D + j] += acc;
}

// final rmsnorm + L2 normalize; writes xng in (D,S) layout.  grid=S, block=D
__global__ __launch_bounds__(128) void k_final(const float* __restrict__ x,
                                               const float* __restrict__ fw,
                                               float* __restrict__ xng) {
    __shared__ float red[D];
    int s = blockIdx.x, j = threadIdx.x;
    float xv = x[s * D + j];
    red[j] = xv * xv;
    __syncthreads();
    for (int off = 64; off > 0; off >>= 1) {
        if (j < off) red[j] += red[j + off];
        __syncthreads();
    }
    float r = 1.0f / sqrtf(red[0] * (1.0f / D) + EPS);
    float y = xv * r * fw[j];
    __syncthreads();
    red[j] = y * y;
    __syncthreads();
    for (int off = 64; off > 0; off >>= 1) {
        if (j < off) red[j] += red[j + off];
        __syncthreads();
    }
    float n = sqrtf(red[0]);
    xng[j * SEQ + s] = y / n;
}

// logits[s,v] = clip(mean_d(xn[s,d] <= vn[v,d] ? 1 : vn[v,d]))
// Block: 64 s x 32 v tile. LDS holds xn^T (d-major) and vn^T tile.
__global__ __launch_bounds__(256) void k_logits(const float* __restrict__ xng,
                                                const float* __restrict__ w_raw,
                                                const float* __restrict__ inv_norm,
                                                float* __restrict__ out) {
    __shared__ float xs[D * 64];   // [d][s'] 32 KB
    __shared__ float vs[D * 32];   // [d][v'] 16 KB
    int t = threadIdx.x;
    int sbase = (blockIdx.x & 1) * 64;
    int vbase = (blockIdx.x >> 1) * 32;
    for (int i = t; i < D * 64; i += 256) {
        int d = i >> 6, s2 = i & 63;
        xs[i] = xng[d * SEQ + sbase + s2];
    }
    for (int i = t; i < D * 32; i += 256) {
        int d = i >> 5, jj = i & 31;
        vs[i] = sigm(w_raw[d * V + vbase + jj]) * inv_norm[vbase + jj];
    }
    __syncthreads();
    int vg = t & 15;   // 16 groups x 2 v
    int sg = t >> 4;   // 16 groups x 4 s
    float acc[4][2] = {};
    for (int d = 0; d < D; ++d) {
        float4 xq = *(const float4*)&xs[d * 64 + sg * 4];
        float2 vq = *(const float2*)&vs[d * 32 + vg * 2];
        float xa0 = xq.x, xa1 = xq.y, xa2 = xq.z, xa3 = xq.w;
        acc[0][0] += (xa0 <= vq.x) ? 1.0f : vq.x;
        acc[0][1] += (xa0 <= vq.y) ? 1.0f : vq.y;
        acc[1][0] += (xa1 <= vq.x) ? 1.0f : vq.x;
        acc[1][1] += (xa1 <= vq.y) ? 1.0f : vq.y;
        acc[2][0] += (xa2 <= vq.x) ? 1.0f : vq.x;
        acc[2][1] += (xa2 <= vq.y) ? 1.0f : vq.y;
        acc[3][0] += (xa3 <= vq.x) ? 1.0f : vq.x;
        acc[3][1] += (xa3 <= vq.y) ? 1.0f : vq.y;
    }
    const float inv128 = 1.0f / 128.0f;
    #pragma unroll
    for (int si = 0; si < 4; ++si) {
        int s = sbase + sg * 4 + si;
        float2 ov;
        ov.x = fminf(fmaxf(acc[si][0] * inv128, 1e-6f), 1.0f - 1e-6f);
        ov.y = fminf(fmaxf(acc[si][1] * inv128, 1e-6f), 1.0f - 1e-6f);
        *(float2*)&out[s * V + vbase + vg * 2] = ov;
    }
}

extern "C" void kernel_launch(void* const* d_in, const int* in_sizes, int n_in,
                              void* d_out, int out_size, void* d_ws, size_t ws_size,
                              hipStream_t stream) {
    const int* idx = (const int*)d_in[0];
    const float* w_raw = (const float*)d_in[1];
    const float* n1w = (const float*)d_in[2];
    const float* n2w = (const float*)d_in[3];
    const float* wq = (const float*)d_in[4];
    const float* wk = (const float*)d_in[5];
    const float* wv = (const float*)d_in[6];
    const float* wo = (const float*)d_in[7];
    const float* w1 = (const float*)d_in[8];
    const float* w3 = (const float*)d_in[9];   // note: setup dict order is w1, w3, w2
    const float* w2 = (const float*)d_in[10];
    const float* fnw = (const float*)d_in[11];
    float* out = (float*)d_out;
    float* ws = (float*)d_ws;

    float* x    = ws;            // 16384
    float* q    = ws + 16384;    // 16384
    float* k    = ws + 32768;    // 16384
    float* v    = ws + 49152;    // 16384
    float* o    = ws + 65536;    // 16384
    float* a    = ws + 81920;    // 43648
    float* xng  = ws + 131072;   // 16384
    float* invn = ws + 147456;   // 8192

    k_embed<<<dim3(64), dim3(256), 0, stream>>>(idx, w_raw, x);
    k_vnorm<<<dim3(32), dim3(256), 0, stream>>>(w_raw, invn);
    for (int l = 0; l < 2; ++l) {
        k_rms_qkv_rope<<<dim3(SEQ), dim3(D), 0, stream>>>(
            x, wq + l * D * D, wk + l * D * D, wv + l * D * D, n1w + l * D, q, k, v);
        k_attn<<<dim3(NH), dim3(SEQ), 0, stream>>>(q, k, v, o);
        k_wo_res_ffn1<<<dim3(SEQ), dim3(D), 0, stream>>>(
            x, o, wo + l * D * D, n2w + l * D, w1 + l * D * HID, w3 + l * D * HID, a);
        k_ffn2<<<dim3(SEQ), dim3(D), 0, stream>>>(x, a, w2 + l * HID * D);
    }
    k_final<<<dim3(SEQ), dim3(D), 0, stream>>>(x, fnw, xng);
    k_logits<<<dim3(512), dim3(256), 0, stream>>>(xng, w_raw, invn, out);
}

// Round 2
// 181.161 us; speedup vs baseline: 1.5922x; 1.5922x over previous
//
#include <hip/hip_runtime.h>
#include <math.h>

#define V 8192
#define D 128
#define NH 8
#define HD 16
#define SEQ 128
#define HID 341
#define EPS 1e-6f

__device__ __forceinline__ float sigm(float x) { return 1.0f / (1.0f + expf(-x)); }

// Block-wide sum of val*val over 128 threads via LDS tree. Safe to reuse `red`
// after return (trailing barrier).
__device__ __forceinline__ float block_sumsq(float* red, int j, float val) {
    red[j] = val * val;
    __syncthreads();
    for (int off = 64; off > 0; off >>= 1) {
        if (j < off) red[j] += red[j + off];
        __syncthreads();
    }
    float s = red[0];
    __syncthreads();
    return s;
}

// K1: x = sigmoid(w_raw.T[idx]); h = rmsnorm(x); q,k,v = h@W; rope(q,k)
// grid=SEQ, block=D
__global__ __launch_bounds__(128) void k_embed_qkv(
    const int* __restrict__ idx, const float* __restrict__ w_raw,
    const float* __restrict__ wq, const float* __restrict__ wk,
    const float* __restrict__ wv, const float* __restrict__ n1w,
    float* __restrict__ x, float* __restrict__ q, float* __restrict__ k,
    float* __restrict__ v) {
    __shared__ float red[D], hr[D], qrow[D], krow[D];
    int s = blockIdx.x, j = threadIdx.x;
    float xv = sigm(w_raw[j * V + idx[s]]);
    x[s * D + j] = xv;
    float ss = block_sumsq(red, j, xv);
    float r = 1.0f / sqrtf(ss * (1.0f / D) + EPS);
    hr[j] = xv * r * n1w[j];
    __syncthreads();
    float qa0 = 0, qa1 = 0, ka0 = 0, ka1 = 0, va0 = 0, va1 = 0;
    for (int d = 0; d < D; d += 2) {
        float h0 = hr[d], h1 = hr[d + 1];
        qa0 += h0 * wq[d * D + j];
        qa1 += h1 * wq[(d + 1) * D + j];
        ka0 += h0 * wk[d * D + j];
        ka1 += h1 * wk[(d + 1) * D + j];
        va0 += h0 * wv[d * D + j];
        va1 += h1 * wv[(d + 1) * D + j];
    }
    v[s * D + j] = va0 + va1;
    qrow[j] = qa0 + qa1;
    krow[j] = ka0 + ka1;
    __syncthreads();
    int c = j & (HD - 1);
    int m = c >> 1;
    float fr = (float)s * expf(-(float)m * 1.15129254649702283e+00f);
    float cs = cosf(fr), sn = sinf(fr);
    int base = j & ~1;
    float qe = qrow[base], qo = qrow[base + 1];
    float ke = krow[base], ko = krow[base + 1];
    q[s * D + j] = (c & 1) ? (qe * sn + qo * cs) : (qe * cs - qo * sn);
    k[s * D + j] = (c & 1) ? (ke * sn + ko * cs) : (ke * cs - ko * sn);
}

// K2/K3: per-row fused: attention + wo + residual + rms2 + FFN + residual,
// then (MODE=0) next layer's rms+qkv+rope, or (MODE=1) final rms + L2 norm.
// grid=SEQ, block=D
template <int MODE>
__global__ __launch_bounds__(128) void k_layer(
    const float* __restrict__ q, const float* __restrict__ kg,
    const float* __restrict__ vg, float* __restrict__ x,
    const float* __restrict__ wo, const float* __restrict__ n2w,
    const float* __restrict__ w1, const float* __restrict__ w3,
    const float* __restrict__ w2,
    // MODE==0:
    const float* __restrict__ wq, const float* __restrict__ wk,
    const float* __restrict__ wv, const float* __restrict__ n1w,
    float* __restrict__ qo, float* __restrict__ ko, float* __restrict__ vo,
    // MODE==1:
    const float* __restrict__ fw, float* __restrict__ xng) {
    __shared__ float ksh[SEQ][D + 1];  // 66 KB, +1 pad -> 2-way (free) conflicts
    __shared__ float ps[NH][SEQ + 1];
    __shared__ float qs[D], red[D], red2[D], orow[D], h2[D];
    __shared__ float mh[NH], rl[NH];
    __shared__ float af[HID];
    int s = blockIdx.x, t = threadIdx.x;

    qs[t] = q[s * D + t];
    for (int r = 0; r < SEQ; ++r) ksh[r][t] = kg[r * D + t];
    __syncthreads();

    // scores: thread j = t computes all 8 head-dots for key row j
    {
        int j = t;
        #pragma unroll
        for (int h = 0; h < NH; ++h) {
            float acc = 0.f;
            #pragma unroll
            for (int c = 0; c < HD; ++c) acc += qs[h * HD + c] * ksh[j][h * HD + c];
            ps[h][j] = acc * 0.25f;
        }
    }
    __syncthreads();

    // softmax over j<=s per head; thread t = (h = t>>4, i16 = t&15)
    int h = t >> 4, i16 = t & 15;
    float pm = -1e30f;
    for (int j = i16; j <= s; j += 16) pm = fmaxf(pm, ps[h][j]);
    red2[t] = pm;
    __syncthreads();
    if (t < NH) {
        float m = -1e30f;
        for (int u = 0; u < 16; ++u) m = fmaxf(m, red2[t * 16 + u]);
        mh[t] = m;
    }
    __syncthreads();
    float m = mh[h];
    float psum = 0.f;
    for (int j = i16; j <= s; j += 16) {
        float e = expf(ps[h][j] - m);
        ps[h][j] = e;
        psum += e;
    }
    red2[t] = psum;
    __syncthreads();
    if (t < NH) {
        float l = 0.f;
        for (int u = 0; u < 16; ++u) l += red2[t * 16 + u];
        rl[t] = 1.0f / l;
    }
    __syncthreads();

    // o[t] = rl[h] * sum_{j<=s} p[h][j] * V[j][t]  (V read coalesced from global)
    float oa0 = 0, oa1 = 0, oa2 = 0, oa3 = 0;
    int j = 0;
    for (; j + 3 <= s; j += 4) {
        oa0 += ps[h][j] * vg[j * D + t];
        oa1 += ps[h][j + 1] * vg[(j + 1) * D + t];
        oa2 += ps[h][j + 2] * vg[(j + 2) * D + t];
        oa3 += ps[h][j + 3] * vg[(j + 3) * D + t];
    }
    for (; j <= s; ++j) oa0 += ps[h][j] * vg[j * D + t];
    orow[t] = ((oa0 + oa1) + (oa2 + oa3)) * rl[h];
    __syncthreads();

    // wo projection + residual
    float w0 = 0, w1a = 0, w2a = 0, w3a = 0;
    for (int d = 0; d < D; d += 4) {
        w0 += orow[d] * wo[d * D + t];
        w1a += orow[d + 1] * wo[(d + 1) * D + t];
        w2a += orow[d + 2] * wo[(d + 2) * D + t];
        w3a += orow[d + 3] * wo[(d + 3) * D + t];
    }
    float xn = x[s * D + t] + ((w0 + w1a) + (w2a + w3a));

    // rms2 + FFN
    float ss2 = block_sumsq(red, t, xn);
    float r2 = 1.0f / sqrtf(ss2 * (1.0f / D) + EPS);
    h2[t] = xn * r2 * n2w[t];
    __syncthreads();
    for (int col = t; col < HID; col += D) {
        float a10 = 0, a11 = 0, a30 = 0, a31 = 0;
        for (int d = 0; d < D; d += 2) {
            float h0 = h2[d], h1 = h2[d + 1];
            a10 += h0 * w1[d * HID + col];
            a11 += h1 * w1[(d + 1) * HID + col];
            a30 += h0 * w3[d * HID + col];
            a31 += h1 * w3[(d + 1) * HID + col];
        }
        float a1 = a10 + a11, a3 = a30 + a31;
        af[col] = (a1 / (1.0f + expf(-a1))) * a3;
    }
    __syncthreads();
    float f0 = 0, f1 = 0, f2 = 0, f3 = 0;
    int tt = 0;
    for (; tt + 4 <= HID; tt += 4) {
        f0 += af[tt] * w2[tt * D + t];
        f1 += af[tt + 1] * w2[(tt + 1) * D + t];
        f2 += af[tt + 2] * w2[(tt + 2) * D + t];
        f3 += af[tt + 3] * w2[(tt + 3) * D + t];
    }
    for (; tt < HID; ++tt) f0 += af[tt] * w2[tt * D + t];
    float x2 = xn + ((f0 + f1) + (f2 + f3));
    x[s * D + t] = x2;

    if constexpr (MODE == 0) {
        // next layer: rms + qkv + rope
        float ss = block_sumsq(red, t, x2);
        float r = 1.0f / sqrtf(ss * (1.0f / D) + EPS);
        h2[t] = x2 * r * n1w[t];
        __syncthreads();
        float qa0 = 0, qa1 = 0, ka0 = 0, ka1 = 0, va0 = 0, va1 = 0;
        for (int d = 0; d < D; d += 2) {
            float h0 = h2[d], h1 = h2[d + 1];
            qa0 += h0 * wq[d * D + t];
            qa1 += h1 * wq[(d + 1) * D + t];
            ka0 += h0 * wk[d * D + t];
            ka1 += h1 * wk[(d + 1) * D + t];
            va0 += h0 * wv[d * D + t];
            va1 += h1 * wv[(d + 1) * D + t];
        }
        vo[s * D + t] = va0 + va1;
        qs[t] = qa0 + qa1;
        orow[t] = ka0 + ka1;
        __syncthreads();
        int c = t & (HD - 1);
        int mm = c >> 1;
        float fr = (float)s * expf(-(float)mm * 1.15129254649702283e+00f);
        float cs = cosf(fr), sn = sinf(fr);
        int base = t & ~1;
        float qe = qs[base], qod = qs[base + 1];
        float ke = orow[base], kod = orow[base + 1];
        qo[s * D + t] = (c & 1) ? (qe * sn + qod * cs) : (qe * cs - qod * sn);
        ko[s * D + t] = (c & 1) ? (ke * sn + kod * cs) : (ke * cs - kod * sn);
    } else {
        // final rms + L2 normalize, write (D,S) layout
        float ss = block_sumsq(red, t, x2);
        float r = 1.0f / sqrtf(ss * (1.0f / D) + EPS);
        float y = x2 * r * fw[t];
        float nn = block_sumsq(red, t, y);
        xng[t * SEQ + s] = y / sqrtf(nn);
    }
}

// K4: logits[s,v] = clip(mean_d(xn[s,d] <= vn[v,d] ? 1 : vn[v,d]))
// 64s x 32v tile per block; vocab-column norm computed in-tile.
__global__ __launch_bounds__(256) void k_logits(const float* __restrict__ xng,
                                                const float* __restrict__ w_raw,
                                                float* __restrict__ out) {
    __shared__ float xs[D * 64];  // [d][s'] 32 KB
    __shared__ float vs[D * 32];  // [d][v'] 16 KB
    __shared__ float nred[256];
    __shared__ float invn_s[32];
    int t = threadIdx.x;
    int sbase = (blockIdx.x & 1) * 64;
    int vbase = (blockIdx.x >> 1) * 32;
    for (int i = t; i < D * 64; i += 256) {
        int d = i >> 6, s2 = i & 63;
        xs[i] = xng[d * SEQ + sbase + s2];
    }
    for (int i = t; i < D * 32; i += 256) {
        int d = i >> 5, jj = i & 31;
        vs[i] = sigm(w_raw[d * V + vbase + jj]);
    }
    __syncthreads();
    // column norms: 8 threads per column, 16 d each
    {
        int col = t & 31, dp = t >> 5;
        float p = 0.f;
        for (int u = 0; u < 16; ++u) {
            float vv = vs[(dp * 16 + u) * 32 + col];
            p += vv * vv;
        }
        nred[t] = p;
    }
    __syncthreads();
    if (t < 32) {
        float sum = 0.f;
        for (int u = 0; u < 8; ++u) sum += nred[u * 32 + t];
        invn_s[t] = 1.0f / sqrtf(sum);
    }
    __syncthreads();
    for (int i = t; i < D * 32; i += 256) vs[i] *= invn_s[i & 31];
    __syncthreads();
    int vg = t & 15;
    int sg = t >> 4;
    float acc[4][2] = {};
    for (int d = 0; d < D; ++d) {
        float4 xq = *(const float4*)&xs[d * 64 + sg * 4];
        float2 vq = *(const float2*)&vs[d * 32 + vg * 2];
        acc[0][0] += (xq.x <= vq.x) ? 1.0f : vq.x;
        acc[0][1] += (xq.x <= vq.y) ? 1.0f : vq.y;
        acc[1][0] += (xq.y <= vq.x) ? 1.0f : vq.x;
        acc[1][1] += (xq.y <= vq.y) ? 1.0f : vq.y;
        acc[2][0] += (xq.z <= vq.x) ? 1.0f : vq.x;
        acc[2][1] += (xq.z <= vq.y) ? 1.0f : vq.y;
        acc[3][0] += (xq.w <= vq.x) ? 1.0f : vq.x;
        acc[3][1] += (xq.w <= vq.y) ? 1.0f : vq.y;
    }
    const float inv128 = 1.0f / 128.0f;
    #pragma unroll
    for (int si = 0; si < 4; ++si) {
        int s = sbase + sg * 4 + si;
        float2 ov;
        ov.x = fminf(fmaxf(acc[si][0] * inv128, 1e-6f), 1.0f - 1e-6f);
        ov.y = fminf(fmaxf(acc[si][1] * inv128, 1e-6f), 1.0f - 1e-6f);
        *(float2*)&out[s * V + vbase + vg * 2] = ov;
    }
}

extern "C" void kernel_launch(void* const* d_in, const int* in_sizes, int n_in,
                              void* d_out, int out_size, void* d_ws, size_t ws_size,
                              hipStream_t stream) {
    const int* idx = (const int*)d_in[0];
    const float* w_raw = (const float*)d_in[1];
    const float* n1w = (const float*)d_in[2];
    const float* n2w = (const float*)d_in[3];
    const float* wq = (const float*)d_in[4];
    const float* wk = (const float*)d_in[5];
    const float* wv = (const float*)d_in[6];
    const float* wo = (const float*)d_in[7];
    const float* w1 = (const float*)d_in[8];
    const float* w3 = (const float*)d_in[9];
    const float* w2 = (const float*)d_in[10];
    const float* fnw = (const float*)d_in[11];
    float* out = (float*)d_out;
    float* ws = (float*)d_ws;

    float* x   = ws;             // 16384
    float* q1  = ws + 16384;
    float* k1  = ws + 32768;
    float* v1  = ws + 49152;
    float* q2  = ws + 65536;
    float* k2  = ws + 81920;
    float* v2  = ws + 98304;
    float* xng = ws + 114688;

    k_embed_qkv<<<dim3(SEQ), dim3(D), 0, stream>>>(idx, w_raw, wq, wk, wv, n1w,
                                                   x, q1, k1, v1);
    k_layer<0><<<dim3(SEQ), dim3(D), 0, stream>>>(
        q1, k1, v1, x, wo, n2w, w1, w3, w2,
        wq + D * D, wk + D * D, wv + D * D, n1w + D, q2, k2, v2,
        (const float*)nullptr, (float*)nullptr);
    k_layer<1><<<dim3(SEQ), dim3(D), 0, stream>>>(
        q2, k2, v2, x, wo + D * D, n2w + D, w1 + D * HID, w3 + D * HID,
        w2 + HID * D, (const float*)nullptr, (const float*)nullptr,
        (const float*)nullptr, (const float*)nullptr, (float*)nullptr,
        (float*)nullptr, (float*)nullptr, fnw, xng);
    k_logits<<<dim3(512), dim3(256), 0, stream>>>(xng, w_raw, out);
}

// Round 3
// 159.168 us; speedup vs baseline: 1.8122x; 1.1382x over previous
//
#include <hip/hip_runtime.h>
#include <math.h>

#define V 8192
#define D 128
#define NH 8
#define HD 16
#define SEQ 128
#define HID 341
#define EPS 1e-6f

__device__ __forceinline__ float sigm(float x) { return 1.0f / (1.0f + expf(-x)); }

// 256-thread block-wide sum. scratch >= 4 floats. 2 barriers.
__device__ __forceinline__ float block_sum256(float v, float* scratch) {
    #pragma unroll
    for (int m = 32; m > 0; m >>= 1) v += __shfl_xor(v, m);
    if ((threadIdx.x & 63) == 0) scratch[threadIdx.x >> 6] = v;
    __syncthreads();
    float s = (scratch[0] + scratch[1]) + (scratch[2] + scratch[3]);
    __syncthreads();
    return s;
}

// QKV projection + rope from normalized row hr[128] (LDS). 256 threads.
// Tasks: t<128 -> q col t ; t>=128 -> k col t-128 ; plus v split in 2 d-halves.
__device__ __forceinline__ void qkv_rope(const float* hr, const float* wq,
                                         const float* wk, const float* wv, int s,
                                         float* qrow, float* krow,
                                         float (*vpart)[D], float* qo, float* ko,
                                         float* vo) {
    int t = threadIdx.x;
    int col = t & 127, half = t >> 7;
    {
        const float* w = (t < 128) ? wq : wk;
        float a0 = 0, a1 = 0;
        #pragma unroll 8
        for (int d = 0; d < D; d += 2) {
            a0 += hr[d] * w[d * D + col];
            a1 += hr[d + 1] * w[(d + 1) * D + col];
        }
        if (t < 128) qrow[col] = a0 + a1;
        else krow[col] = a0 + a1;
    }
    {
        int dlo = half * 64;
        float a0 = 0, a1 = 0;
        #pragma unroll 8
        for (int d = dlo; d < dlo + 64; d += 2) {
            a0 += hr[d] * wv[d * D + col];
            a1 += hr[d + 1] * wv[(d + 1) * D + col];
        }
        vpart[half][col] = a0 + a1;
    }
    __syncthreads();
    if (t < 128) {
        vo[s * D + t] = vpart[0][t] + vpart[1][t];
        int c = t & (HD - 1);
        int m = c >> 1;
        float fr = (float)s * expf(-(float)m * 1.15129254649702283e+00f);
        float cs = cosf(fr), sn = sinf(fr);
        int base = t & ~1;
        float qe = qrow[base], qod = qrow[base + 1];
        float ke = krow[base], kod = krow[base + 1];
        qo[s * D + t] = (c & 1) ? (qe * sn + qod * cs) : (qe * cs - qod * sn);
        ko[s * D + t] = (c & 1) ? (ke * sn + kod * cs) : (ke * cs - kod * sn);
    }
}

// K1: embed + rms + qkv + rope.  grid=SEQ, block=256
__global__ __launch_bounds__(256) void k_embed_qkv(
    const int* __restrict__ idx, const float* __restrict__ w_raw,
    const float* __restrict__ wq, const float* __restrict__ wk,
    const float* __restrict__ wv, const float* __restrict__ n1w,
    float* __restrict__ x, float* __restrict__ q, float* __restrict__ k,
    float* __restrict__ v) {
    __shared__ float hr[D], qrow[D], krow[D], vpart[2][D], scr[4];
    int s = blockIdx.x, t = threadIdx.x;
    float xv = 0.f;
    if (t < 128) {
        xv = sigm(w_raw[t * V + idx[s]]);
        x[s * D + t] = xv;
    }
    float ss = block_sum256(xv * xv, scr);
    float r = 1.0f / sqrtf(ss * (1.0f / D) + EPS);
    if (t < 128) hr[t] = xv * r * n1w[t];
    __syncthreads();
    qkv_rope(hr, wq, wk, wv, s, qrow, krow, vpart, q, k, v);
}

// K2/K3: fused layer per row.  grid=SEQ, block=256
template <int MODE>
__global__ __launch_bounds__(256) void k_layer(
    const float* __restrict__ q, const float* __restrict__ kg,
    const float* __restrict__ vg, float* __restrict__ x,
    const float* __restrict__ wo, const float* __restrict__ n2w,
    const float* __restrict__ w1, const float* __restrict__ w3,
    const float* __restrict__ w2, const float* __restrict__ wq,
    const float* __restrict__ wk, const float* __restrict__ wv,
    const float* __restrict__ n1w, float* __restrict__ qo, float* __restrict__ ko,
    float* __restrict__ vo, const float* __restrict__ fw, float* __restrict__ xng) {
    __shared__ float ps[NH][SEQ + 1];
    __shared__ float qs[D], orow[D], h2[D];
    __shared__ float part[2][D];
    __shared__ float qrow[D], krow[D];
    __shared__ float afA[HID], afB[HID], af[HID];
    __shared__ float rl[NH];
    __shared__ float scr[4];
    int s = blockIdx.x, t = threadIdx.x;
    int col = t & 127, half = t >> 7;

    float xr = 0.f;
    if (t < 128) {
        qs[t] = q[s * D + t];
        xr = x[s * D + t];
    }
    __syncthreads();

    // scores: thread handles (j=col, h=half+2u) for u=0..3; K read direct from L2
    {
        int j = col;
        #pragma unroll
        for (int u = 0; u < 4; ++u) {
            int h = half + 2 * u;
            const float4* kp = (const float4*)&kg[j * D + h * HD];
            float4 ka = kp[0], kb = kp[1], kc = kp[2], kd = kp[3];
            const float* qh = &qs[h * HD];
            float acc = ka.x * qh[0] + ka.y * qh[1] + ka.z * qh[2] + ka.w * qh[3] +
                        kb.x * qh[4] + kb.y * qh[5] + kb.z * qh[6] + kb.w * qh[7] +
                        kc.x * qh[8] + kc.y * qh[9] + kc.z * qh[10] + kc.w * qh[11] +
                        kd.x * qh[12] + kd.y * qh[13] + kd.z * qh[14] + kd.w * qh[15];
            ps[h][j] = acc * 0.25f;
        }
    }
    __syncthreads();

    // softmax over j<=s: head h = t>>5, 32 lanes each (within one wave)
    {
        int h = t >> 5, lane = t & 31;
        float pm = -1e30f;
        for (int j = lane; j <= s; j += 32) pm = fmaxf(pm, ps[h][j]);
        #pragma unroll
        for (int m = 16; m > 0; m >>= 1) pm = fmaxf(pm, __shfl_xor(pm, m, 32));
        float psum = 0.f;
        for (int j = lane; j <= s; j += 32) {
            float e = expf(ps[h][j] - pm);
            ps[h][j] = e;
            psum += e;
        }
        #pragma unroll
        for (int m = 16; m > 0; m >>= 1) psum += __shfl_xor(psum, m, 32);
        if (lane == 0) rl[h] = 1.0f / psum;
    }
    __syncthreads();

    // o: col output, j split in 2 halves across `half`
    {
        int h = col >> 4;
        int jlo = half * 64;
        int jhi = (s < jlo + 63) ? s : (jlo + 63);
        float a0 = 0, a1 = 0, a2 = 0, a3 = 0;
        int j = jlo;
        #pragma unroll 4
        for (; j + 3 <= jhi; j += 4) {
            a0 += ps[h][j] * vg[j * D + col];
            a1 += ps[h][j + 1] * vg[(j + 1) * D + col];
            a2 += ps[h][j + 2] * vg[(j + 2) * D + col];
            a3 += ps[h][j + 3] * vg[(j + 3) * D + col];
        }
        for (; j <= jhi; ++j) a0 += ps[h][j] * vg[j * D + col];
        part[half][col] = (a0 + a1) + (a2 + a3);
    }
    __syncthreads();
    if (t < 128) orow[t] = (part[0][t] + part[1][t]) * rl[t >> 4];
    __syncthreads();

    // wo: col output, d split in 2 halves
    {
        int dlo = half * 64;
        float a0 = 0, a1 = 0;
        #pragma unroll 8
        for (int d = dlo; d < dlo + 64; d += 2) {
            a0 += orow[d] * wo[d * D + col];
            a1 += orow[d + 1] * wo[(d + 1) * D + col];
        }
        part[half][col] = a0 + a1;
    }
    __syncthreads();
    float xn = 0.f;
    if (t < 128) xn = xr + part[0][t] + part[1][t];
    float ss2 = block_sum256((t < 128) ? xn * xn : 0.f, scr);
    float r2 = 1.0f / sqrtf(ss2 * (1.0f / D) + EPS);
    if (t < 128) h2[t] = xn * r2 * n2w[t];
    __syncthreads();

    // FFN1: 682 column-tasks
    for (int task = t; task < 2 * HID; task += 256) {
        int mat = task >= HID;
        int c2 = mat ? (task - HID) : task;
        const float* w = mat ? w3 : w1;
        float a0 = 0, a1 = 0;
        #pragma unroll 8
        for (int d = 0; d < D; d += 2) {
            a0 += h2[d] * w[d * HID + c2];
            a1 += h2[d + 1] * w[(d + 1) * HID + c2];
        }
        if (mat) afB[c2] = a0 + a1;
        else afA[c2] = a0 + a1;
    }
    __syncthreads();
    for (int c2 = t; c2 < HID; c2 += 256) {
        float a1v = afA[c2];
        af[c2] = (a1v / (1.0f + expf(-a1v))) * afB[c2];
    }
    __syncthreads();

    // FFN2: col output, 341-sum split in 2
    {
        int lo = half * 171;
        int hi = half ? HID : 171;
        float a0 = 0, a1 = 0;
        int tt = lo;
        #pragma unroll 8
        for (; tt + 1 < hi; tt += 2) {
            a0 += af[tt] * w2[tt * D + col];
            a1 += af[tt + 1] * w2[(tt + 1) * D + col];
        }
        for (; tt < hi; ++tt) a0 += af[tt] * w2[tt * D + col];
        part[half][col] = a0 + a1;
    }
    __syncthreads();
    float x2 = 0.f;
    if (t < 128) {
        x2 = xn + part[0][t] + part[1][t];
        if (MODE == 0) x[s * D + t] = x2;
    }

    if constexpr (MODE == 0) {
        float ss = block_sum256((t < 128) ? x2 * x2 : 0.f, scr);
        float r = 1.0f / sqrtf(ss * (1.0f / D) + EPS);
        if (t < 128) h2[t] = x2 * r * n1w[t];
        __syncthreads();
        qkv_rope(h2, wq, wk, wv, s, qrow, krow, part, qo, ko, vo);
    } else {
        float ss = block_sum256((t < 128) ? x2 * x2 : 0.f, scr);
        float r = 1.0f / sqrtf(ss * (1.0f / D) + EPS);
        float y = (t < 128) ? x2 * r * fw[t] : 0.f;
        float nn = block_sum256(y * y, scr);
        if (t < 128) xng[t * SEQ + s] = y / sqrtf(nn);
    }
}

// K4: logits[s,v] = clip(mean_d(xn[s,d] <= vn[v,d] ? 1 : vn[v,d]))
__global__ __launch_bounds__(256) void k_logits(const float* __restrict__ xng,
                                                const float* __restrict__ w_raw,
                                                float* __restrict__ out) {
    __shared__ float xs[D * 64];
    __shared__ float vs[D * 32];
    __shared__ float nred[256];
    __shared__ float invn_s[32];
    int t = threadIdx.x;
    int sbase = (blockIdx.x & 1) * 64;
    int vbase = (blockIdx.x >> 1) * 32;
    for (int i = t; i < D * 64; i += 256) {
        int d = i >> 6, s2 = i & 63;
        xs[i] = xng[d * SEQ + sbase + s2];
    }
    for (int i = t; i < D * 32; i += 256) {
        int d = i >> 5, jj = i & 31;
        vs[i] = sigm(w_raw[d * V + vbase + jj]);
    }
    __syncthreads();
    {
        int colc = t & 31, dp = t >> 5;
        float p = 0.f;
        for (int u = 0; u < 16; ++u) {
            float vv = vs[(dp * 16 + u) * 32 + colc];
            p += vv * vv;
        }
        nred[t] = p;
    }
    __syncthreads();
    if (t < 32) {
        float sum = 0.f;
        for (int u = 0; u < 8; ++u) sum += nred[u * 32 + t];
        invn_s[t] = 1.0f / sqrtf(sum);
    }
    __syncthreads();
    for (int i = t; i < D * 32; i += 256) vs[i] *= invn_s[i & 31];
    __syncthreads();
    int vg = t & 15;
    int sg = t >> 4;
    float acc[4][2] = {};
    for (int d = 0; d < D; ++d) {
        float4 xq = *(const float4*)&xs[d * 64 + sg * 4];
        float2 vq = *(const float2*)&vs[d * 32 + vg * 2];
        acc[0][0] += (xq.x <= vq.x) ? 1.0f : vq.x;
        acc[0][1] += (xq.x <= vq.y) ? 1.0f : vq.y;
        acc[1][0] += (xq.y <= vq.x) ? 1.0f : vq.x;
        acc[1][1] += (xq.y <= vq.y) ? 1.0f : vq.y;
        acc[2][0] += (xq.z <= vq.x) ? 1.0f : vq.x;
        acc[2][1] += (xq.z <= vq.y) ? 1.0f : vq.y;
        acc[3][0] += (xq.w <= vq.x) ? 1.0f : vq.x;
        acc[3][1] += (xq.w <= vq.y) ? 1.0f : vq.y;
    }
    const float inv128 = 1.0f / 128.0f;
    #pragma unroll
    for (int si = 0; si < 4; ++si) {
        int s = sbase + sg * 4 + si;
        float2 ov;
        ov.x = fminf(fmaxf(acc[si][0] * inv128, 1e-6f), 1.0f - 1e-6f);
        ov.y = fminf(fmaxf(acc[si][1] * inv128, 1e-6f), 1.0f - 1e-6f);
        *(float2*)&out[s * V + vbase + vg * 2] = ov;
    }
}

extern "C" void kernel_launch(void* const* d_in, const int* in_sizes, int n_in,
                              void* d_out, int out_size, void* d_ws, size_t ws_size,
                              hipStream_t stream) {
    const int* idx = (const int*)d_in[0];
    const float* w_raw = (const float*)d_in[1];
    const float* n1w = (const float*)d_in[2];
    const float* n2w = (const float*)d_in[3];
    const float* wq = (const float*)d_in[4];
    const float* wk = (const float*)d_in[5];
    const float* wv = (const float*)d_in[6];
    const float* wo = (const float*)d_in[7];
    const float* w1 = (const float*)d_in[8];
    const float* w3 = (const float*)d_in[9];
    const float* w2 = (const float*)d_in[10];
    const float* fnw = (const float*)d_in[11];
    float* out = (float*)d_out;
    float* ws = (float*)d_ws;

    float* x   = ws;
    float* q1  = ws + 16384;
    float* k1  = ws + 32768;
    float* v1  = ws + 49152;
    float* q2  = ws + 65536;
    float* k2  = ws + 81920;
    float* v2  = ws + 98304;
    float* xng = ws + 114688;

    k_embed_qkv<<<dim3(SEQ), dim3(256), 0, stream>>>(idx, w_raw, wq, wk, wv, n1w,
                                                     x, q1, k1, v1);
    k_layer<0><<<dim3(SEQ), dim3(256), 0, stream>>>(
        q1, k1, v1, x, wo, n2w, w1, w3, w2,
        wq + D * D, wk + D * D, wv + D * D, n1w + D, q2, k2, v2,
        (const float*)nullptr, (float*)nullptr);
    k_layer<1><<<dim3(SEQ), dim3(256), 0, stream>>>(
        q2, k2, v2, x, wo + D * D, n2w + D, w1 + D * HID, w3 + D * HID,
        w2 + HID * D, (const float*)nullptr, (const float*)nullptr,
        (const float*)nullptr, (const float*)nullptr, (float*)nullptr,
        (float*)nullptr, (float*)nullptr, fnw, xng);
    k_logits<<<dim3(512), dim3(256), 0, stream>>>(xng, w_raw, out);
}

// Round 4
// 146.369 us; speedup vs baseline: 1.9706x; 1.0874x over previous
//
#include <hip/hip_runtime.h>
#include <math.h>

#define V 8192
#define D 128
#define NH 8
#define HD 16
#define SEQ 128
#define HID 341
#define EPS 1e-6f

__device__ __forceinline__ float sigm(float x) { return 1.0f / (1.0f + __expf(-x)); }

// 256-thread block-wide sum. scratch >= 4 floats. 2 barriers.
__device__ __forceinline__ float block_sum256(float v, float* scratch) {
    #pragma unroll
    for (int m = 32; m > 0; m >>= 1) v += __shfl_xor(v, m);
    if ((threadIdx.x & 63) == 0) scratch[threadIdx.x >> 6] = v;
    __syncthreads();
    float s = (scratch[0] + scratch[1]) + (scratch[2] + scratch[3]);
    __syncthreads();
    return s;
}

// K1: embed + rms + qkv + rope. grid = SEQ + 256 (warm blocks), block=256
__global__ __launch_bounds__(256, 1) void k_embed_qkv(
    const int* __restrict__ idx, const float* __restrict__ w_raw,
    const float* __restrict__ wq, const float* __restrict__ wk,
    const float* __restrict__ wv, const float* __restrict__ n1w,
    const float* __restrict__ w1, const float* __restrict__ w3,
    const float* __restrict__ w2, const float* __restrict__ wo,
    float* __restrict__ x, float* __restrict__ q, float* __restrict__ k,
    float* __restrict__ v, float* __restrict__ sink) {
    int t = threadIdx.x;
    if (blockIdx.x >= SEQ) {
        // L3-warm: stream every weight once (w_raw 4MB + layers ~1.8MB)
        int g = (blockIdx.x - SEQ) * 256 + t;  // 0..65535
        float acc = 0.f;
        const float4* p = (const float4*)w_raw;  // 262144 float4
        for (int i = g; i < 262144; i += 65536) {
            float4 u = p[i];
            acc += u.x + u.y + u.z + u.w;
        }
        p = (const float4*)w1;  // 21824 float4 (both layers)
        if (g < 21824) { float4 u = p[g]; acc += u.x + u.y + u.z + u.w; }
        p = (const float4*)w3;
        if (g < 21824) { float4 u = p[g]; acc += u.x + u.y + u.z + u.w; }
        p = (const float4*)w2;
        if (g < 21824) { float4 u = p[g]; acc += u.x + u.y + u.z + u.w; }
        p = (const float4*)wq;  // 8192 float4 (both layers)
        if (g < 8192) { float4 u = p[g]; acc += u.x + u.y + u.z + u.w; }
        p = (const float4*)wk;
        if (g < 8192) { float4 u = p[g]; acc += u.x + u.y + u.z + u.w; }
        p = (const float4*)wv;
        if (g < 8192) { float4 u = p[g]; acc += u.x + u.y + u.z + u.w; }
        p = (const float4*)wo;
        if (g < 8192) { float4 u = p[g]; acc += u.x + u.y + u.z + u.w; }
        if (acc == 1234.5678f) sink[0] = acc;  // never true; defeats DCE
        return;
    }
    __shared__ float hr[D], qrow[D], krow[D], vpart[2][D], scr[4];
    int s = blockIdx.x;
    int col = t & 127, half = t >> 7, dlo = half * 64;
    // embed gather (critical path) issued first
    float xv = 0.f;
    if (t < 128) xv = sigm(w_raw[t * V + idx[s]]);
    // prefetch QKV weight columns into registers (pure tid function)
    float wpre[128];
    const float* wsel = (t < 128) ? wq : wk;
    #pragma unroll
    for (int d = 0; d < 128; ++d) wpre[d] = wsel[d * D + col];
    float wvpre[64];
    #pragma unroll
    for (int d = 0; d < 64; ++d) wvpre[d] = wv[(dlo + d) * D + col];
    if (t < 128) x[s * D + t] = xv;
    float ss = block_sum256(xv * xv, scr);
    float r = 1.0f / sqrtf(ss * (1.0f / D) + EPS);
    if (t < 128) hr[t] = xv * r * n1w[t];
    __syncthreads();
    float a0 = 0, a1 = 0, a2 = 0, a3 = 0;
    #pragma unroll
    for (int d = 0; d < 128; d += 4) {
        a0 += hr[d] * wpre[d];
        a1 += hr[d + 1] * wpre[d + 1];
        a2 += hr[d + 2] * wpre[d + 2];
        a3 += hr[d + 3] * wpre[d + 3];
    }
    float qk = (a0 + a1) + (a2 + a3);
    float b0 = 0, b1 = 0, b2 = 0, b3 = 0;
    #pragma unroll
    for (int d = 0; d < 64; d += 4) {
        b0 += hr[dlo + d] * wvpre[d];
        b1 += hr[dlo + d + 1] * wvpre[d + 1];
        b2 += hr[dlo + d + 2] * wvpre[d + 2];
        b3 += hr[dlo + d + 3] * wvpre[d + 3];
    }
    vpart[half][col] = (b0 + b1) + (b2 + b3);
    if (t < 128) qrow[col] = qk;
    else krow[col] = qk;
    __syncthreads();
    if (t < 128) {
        v[s * D + t] = vpart[0][t] + vpart[1][t];
        int c = t & (HD - 1);
        int m = c >> 1;
        float fr = (float)s * expf(-(float)m * 1.15129254649702283e+00f);
        float cs = cosf(fr), sn = sinf(fr);
        int base = t & ~1;
        float qe = qrow[base], qod = qrow[base + 1];
        float ke = krow[base], kod = krow[base + 1];
        q[s * D + t] = (c & 1) ? (qe * sn + qod * cs) : (qe * cs - qod * sn);
        k[s * D + t] = (c & 1) ? (ke * sn + kod * cs) : (ke * cs - kod * sn);
    }
}

// K2/K3: fused layer per row. grid=SEQ, block=256
template <int MODE>
__global__ __launch_bounds__(256, 1) void k_layer(
    const float* __restrict__ q, const float* __restrict__ kg,
    const float* __restrict__ vg, float* __restrict__ x,
    const float* __restrict__ wo, const float* __restrict__ n2w,
    const float* __restrict__ w1, const float* __restrict__ w3,
    const float* __restrict__ w2, const float* __restrict__ wq,
    const float* __restrict__ wk, const float* __restrict__ wv,
    const float* __restrict__ n1w, float* __restrict__ qo, float* __restrict__ ko,
    float* __restrict__ vo, const float* __restrict__ fw, float* __restrict__ xng) {
    __shared__ float ps[NH][SEQ + 1];
    __shared__ float qs[D], orow[D], h2[D];
    __shared__ float part[2][D];
    __shared__ float afA[HID], afB[HID], af[HID];
    __shared__ float rl[NH];
    __shared__ float scr[4];
    int s = blockIdx.x, t = threadIdx.x;
    int col = t & 127, half = t >> 7;
    int jlo = half * 64, dlo = half * 64;

    // activation loads first (critical path)
    float qv = 0.f, xr = 0.f;
    if (t < 128) {
        qv = q[s * D + t];
        xr = x[s * D + t];
    }
    // register prefetch: K slices (scores), V (o-stage), wo — pending across barriers
    float4 kp[4][4];
    #pragma unroll
    for (int u = 0; u < 4; ++u) {
        const float4* p = (const float4*)&kg[col * D + (half + 2 * u) * HD];
        kp[u][0] = p[0]; kp[u][1] = p[1]; kp[u][2] = p[2]; kp[u][3] = p[3];
    }
    float vpre[64];
    #pragma unroll
    for (int j = 0; j < 64; ++j) vpre[j] = vg[(jlo + j) * D + col];
    float wopre[64];
    #pragma unroll
    for (int u = 0; u < 64; ++u) wopre[u] = wo[(dlo + u) * D + col];

    if (t < 128) qs[t] = qv;
    __syncthreads();

    // scores: thread (j=col, h=half+2u); zero-fill j>s so o-stage is unconditional
    #pragma unroll
    for (int u = 0; u < 4; ++u) {
        int h = half + 2 * u;
        const float* qh = &qs[h * HD];
        float acc = kp[u][0].x * qh[0] + kp[u][0].y * qh[1] + kp[u][0].z * qh[2] +
                    kp[u][0].w * qh[3] + kp[u][1].x * qh[4] + kp[u][1].y * qh[5] +
                    kp[u][1].z * qh[6] + kp[u][1].w * qh[7] + kp[u][2].x * qh[8] +
                    kp[u][2].y * qh[9] + kp[u][2].z * qh[10] + kp[u][2].w * qh[11] +
                    kp[u][3].x * qh[12] + kp[u][3].y * qh[13] + kp[u][3].z * qh[14] +
                    kp[u][3].w * qh[15];
        ps[h][col] = (col <= s) ? acc * 0.25f : 0.f;
    }
    __syncthreads();

    // softmax over j<=s: head h = t>>5, 32 lanes each
    {
        int h = t >> 5, lane = t & 31;
        float pm = -1e30f;
        for (int j = lane; j <= s; j += 32) pm = fmaxf(pm, ps[h][j]);
        #pragma unroll
        for (int m = 16; m > 0; m >>= 1) pm = fmaxf(pm, __shfl_xor(pm, m, 32));
        float psum = 0.f;
        for (int j = lane; j <= s; j += 32) {
            float e = __expf(ps[h][j] - pm);
            ps[h][j] = e;
            psum += e;
        }
        #pragma unroll
        for (int m = 16; m > 0; m >>= 1) psum += __shfl_xor(psum, m, 32);
        if (lane == 0) rl[h] = 1.0f / psum;
    }
    __syncthreads();

    // o partials from prefetched V (ps zero beyond s)
    {
        int h = col >> 4;
        float a0 = 0, a1 = 0, a2 = 0, a3 = 0;
        #pragma unroll
        for (int j = 0; j < 64; j += 4) {
            a0 += ps[h][jlo + j] * vpre[j];
            a1 += ps[h][jlo + j + 1] * vpre[j + 1];
            a2 += ps[h][jlo + j + 2] * vpre[j + 2];
            a3 += ps[h][jlo + j + 3] * vpre[j + 3];
        }
        part[half][col] = (a0 + a1) + (a2 + a3);
    }
    __syncthreads();
    if (t < 128) orow[t] = (part[0][t] + part[1][t]) * rl[t >> 4];
    __syncthreads();

    // wo from prefetched registers
    {
        float a0 = 0, a1 = 0;
        #pragma unroll
        for (int u = 0; u < 64; u += 2) {
            a0 += orow[dlo + u] * wopre[u];
            a1 += orow[dlo + u + 1] * wopre[u + 1];
        }
        part[half][col] = a0 + a1;
    }
    __syncthreads();
    float xn = 0.f;
    if (t < 128) xn = xr + part[0][t] + part[1][t];
    float ss2 = block_sum256((t < 128) ? xn * xn : 0.f, scr);
    float r2 = 1.0f / sqrtf(ss2 * (1.0f / D) + EPS);
    if (t < 128) h2[t] = xn * r2 * n2w[t];
    __syncthreads();

    // FFN1: 682 column-tasks, 32 loads in flight
    for (int task = t; task < 2 * HID; task += 256) {
        int mat = task >= HID;
        int c2 = mat ? (task - HID) : task;
        const float* w = mat ? w3 : w1;
        float a0 = 0, a1 = 0, a2 = 0, a3 = 0;
        #pragma unroll 8
        for (int d = 0; d < D; d += 4) {
            a0 += h2[d] * w[d * HID + c2];
            a1 += h2[d + 1] * w[(d + 1) * HID + c2];
            a2 += h2[d + 2] * w[(d + 2) * HID + c2];
            a3 += h2[d + 3] * w[(d + 3) * HID + c2];
        }
        if (mat) afB[c2] = (a0 + a1) + (a2 + a3);
        else afA[c2] = (a0 + a1) + (a2 + a3);
    }
    __syncthreads();
    for (int c2 = t; c2 < HID; c2 += 256) {
        float a1v = afA[c2];
        af[c2] = (a1v / (1.0f + __expf(-a1v))) * afB[c2];
    }
    __syncthreads();

    // FFN2: col output, 341-sum split [0,171)/[171,341)
    {
        int lo = half ? 171 : 0;
        int hi = half ? 341 : 171;
        float a0 = 0, a1 = 0, a2 = 0, a3 = 0;
        int tt = lo;
        #pragma unroll 8
        for (; tt + 3 < hi; tt += 4) {
            a0 += af[tt] * w2[tt * D + col];
            a1 += af[tt + 1] * w2[(tt + 1) * D + col];
            a2 += af[tt + 2] * w2[(tt + 2) * D + col];
            a3 += af[tt + 3] * w2[(tt + 3) * D + col];
        }
        for (; tt < hi; ++tt) a0 += af[tt] * w2[tt * D + col];
        part[half][col] = (a0 + a1) + (a2 + a3);
    }
    __syncthreads();
    float x2 = 0.f;
    if (t < 128) {
        x2 = xn + part[0][t] + part[1][t];
        if (MODE == 0) x[s * D + t] = x2;
    }

    float ss = block_sum256((t < 128) ? x2 * x2 : 0.f, scr);
    float r = 1.0f / sqrtf(ss * (1.0f / D) + EPS);

    if constexpr (MODE == 0) {
        if (t < 128) h2[t] = x2 * r * n1w[t];
        __syncthreads();
        // next-layer QKV (streamed, 32 in flight) + rope
        const float* wsel = (t < 128) ? wq : wk;
        float a0 = 0, a1 = 0, a2 = 0, a3 = 0;
        #pragma unroll 8
        for (int d = 0; d < D; d += 4) {
            a0 += h2[d] * wsel[d * D + col];
            a1 += h2[d + 1] * wsel[(d + 1) * D + col];
            a2 += h2[d + 2] * wsel[(d + 2) * D + col];
            a3 += h2[d + 3] * wsel[(d + 3) * D + col];
        }
        float qk = (a0 + a1) + (a2 + a3);
        float b0 = 0, b1 = 0, b2 = 0, b3 = 0;
        #pragma unroll 8
        for (int d = dlo; d < dlo + 64; d += 4) {
            b0 += h2[d] * wv[d * D + col];
            b1 += h2[d + 1] * wv[(d + 1) * D + col];
            b2 += h2[d + 2] * wv[(d + 2) * D + col];
            b3 += h2[d + 3] * wv[(d + 3) * D + col];
        }
        part[half][col] = (b0 + b1) + (b2 + b3);
        if (t < 128) qs[col] = qk;
        else orow[col] = qk;
        __syncthreads();
        if (t < 128) {
            vo[s * D + t] = part[0][t] + part[1][t];
            int c = t & (HD - 1);
            int mm = c >> 1;
            float fr = (float)s * expf(-(float)mm * 1.15129254649702283e+00f);
            float cs = cosf(fr), sn = sinf(fr);
            int base = t & ~1;
            float qe = qs[base], qod = qs[base + 1];
            float ke = orow[base], kod = orow[base + 1];
            qo[s * D + t] = (c & 1) ? (qe * sn + qod * cs) : (qe * cs - qod * sn);
            ko[s * D + t] = (c & 1) ? (ke * sn + kod * cs) : (ke * cs - kod * sn);
        }
    } else {
        float y = (t < 128) ? x2 * r * fw[t] : 0.f;
        float nn = block_sum256(y * y, scr);
        if (t < 128) xng[t * SEQ + s] = y / sqrtf(nn);
    }
}

// K4: logits[s,v] = clip(mean_d(xn[s,d] <= vn[v,d] ? 1 : vn[v,d]))
__global__ __launch_bounds__(256) void k_logits(const float* __restrict__ xng,
                                                const float* __restrict__ w_raw,
                                                float* __restrict__ out) {
    __shared__ float xs[D * 64];
    __shared__ float vs[D * 32];
    __shared__ float nred[256];
    __shared__ float invn_s[32];
    int t = threadIdx.x;
    int sbase = (blockIdx.x & 1) * 64;
    int vbase = (blockIdx.x >> 1) * 32;
    for (int i = t; i < D * 64; i += 256) {
        int d = i >> 6, s2 = i & 63;
        xs[i] = xng[d * SEQ + sbase + s2];
    }
    for (int i = t; i < D * 32; i += 256) {
        int d = i >> 5, jj = i & 31;
        vs[i] = sigm(w_raw[d * V + vbase + jj]);
    }
    __syncthreads();
    {
        int colc = t & 31, dp = t >> 5;
        float p = 0.f;
        for (int u = 0; u < 16; ++u) {
            float vv = vs[(dp * 16 + u) * 32 + colc];
            p += vv * vv;
        }
        nred[t] = p;
    }
    __syncthreads();
    if (t < 32) {
        float sum = 0.f;
        for (int u = 0; u < 8; ++u) sum += nred[u * 32 + t];
        invn_s[t] = 1.0f / sqrtf(sum);
    }
    __syncthreads();
    for (int i = t; i < D * 32; i += 256) vs[i] *= invn_s[i & 31];
    __syncthreads();
    int vg = t & 15;
    int sg = t >> 4;
    float acc[4][2] = {};
    for (int d = 0; d < D; ++d) {
        float4 xq = *(const float4*)&xs[d * 64 + sg * 4];
        float2 vq = *(const float2*)&vs[d * 32 + vg * 2];
        acc[0][0] += (xq.x <= vq.x) ? 1.0f : vq.x;
        acc[0][1] += (xq.x <= vq.y) ? 1.0f : vq.y;
        acc[1][0] += (xq.y <= vq.x) ? 1.0f : vq.x;
        acc[1][1] += (xq.y <= vq.y) ? 1.0f : vq.y;
        acc[2][0] += (xq.z <= vq.x) ? 1.0f : vq.x;
        acc[2][1] += (xq.z <= vq.y) ? 1.0f : vq.y;
        acc[3][0] += (xq.w <= vq.x) ? 1.0f : vq.x;
        acc[3][1] += (xq.w <= vq.y) ? 1.0f : vq.y;
    }
    const float inv128 = 1.0f / 128.0f;
    #pragma unroll
    for (int si = 0; si < 4; ++si) {
        int s = sbase + sg * 4 + si;
        float2 ov;
        ov.x = fminf(fmaxf(acc[si][0] * inv128, 1e-6f), 1.0f - 1e-6f);
        ov.y = fminf(fmaxf(acc[si][1] * inv128, 1e-6f), 1.0f - 1e-6f);
        *(float2*)&out[s * V + vbase + vg * 2] = ov;
    }
}

extern "C" void kernel_launch(void* const* d_in, const int* in_sizes, int n_in,
                              void* d_out, int out_size, void* d_ws, size_t ws_size,
                              hipStream_t stream) {
    const int* idx = (const int*)d_in[0];
    const float* w_raw = (const float*)d_in[1];
    const float* n1w = (const float*)d_in[2];
    const float* n2w = (const float*)d_in[3];
    const float* wq = (const float*)d_in[4];
    const float* wk = (const float*)d_in[5];
    const float* wv = (const float*)d_in[6];
    const float* wo = (const float*)d_in[7];
    const float* w1 = (const float*)d_in[8];
    const float* w3 = (const float*)d_in[9];
    const float* w2 = (const float*)d_in[10];
    const float* fnw = (const float*)d_in[11];
    float* out = (float*)d_out;
    float* ws = (float*)d_ws;

    float* x    = ws;
    float* q1   = ws + 16384;
    float* k1   = ws + 32768;
    float* v1   = ws + 49152;
    float* q2   = ws + 65536;
    float* k2   = ws + 81920;
    float* v2   = ws + 98304;
    float* xng  = ws + 114688;
    float* sink = ws + 131072;

    k_embed_qkv<<<dim3(SEQ + 256), dim3(256), 0, stream>>>(
        idx, w_raw, wq, wk, wv, n1w, w1, w3, w2, wo, x, q1, k1, v1, sink);
    k_layer<0><<<dim3(SEQ), dim3(256), 0, stream>>>(
        q1, k1, v1, x, wo, n2w, w1, w3, w2,
        wq + D * D, wk + D * D, wv + D * D, n1w + D, q2, k2, v2,
        (const float*)nullptr, (float*)nullptr);
    k_layer<1><<<dim3(SEQ), dim3(256), 0, stream>>>(
        q2, k2, v2, x, wo + D * D, n2w + D, w1 + D * HID, w3 + D * HID,
        w2 + HID * D, (const float*)nullptr, (const float*)nullptr,
        (const float*)nullptr, (const float*)nullptr, (float*)nullptr,
        (float*)nullptr, (float*)nullptr, fnw, xng);
    k_logits<<<dim3(512), dim3(256), 0, stream>>>(xng, w_raw, out);
}